// Round 10
// baseline (61.906 us; speedup 1.0000x reference)
//
#include <hip/hip_runtime.h>
#include <hip/hip_bf16.h>

// arDCA: out[n,q] = softmax_q( h[400,q] + sum_{j<400} J[400,q,j,tok(n,j)] )
// R10 = R9 MFMA-GEMM streamer with latency/pollution fixes:
//   - 16 waves/CU (256 blocks x 1024 thr; 16 k-slices of 544, 17 steps)
//   - nontemporal X loads (one-pass stream, no L2/L3 fill)
// logits = X[4096 x 8400] * W[8400 x 21], W[k][q] = J[(8400+q)*10752 + k].
// K0: Bt[col(32)][k(8704)] bf16, zero-padded (557 KB, L2-resident).
// N=4096, RES=400, Q=21, L=512.

#define QA    21
#define KVAL  8400
#define KPAD  8704               // 16 slices * 544 ; 544 = 17 steps * 32
#define SLICE 544
#define NSTEP 17
#define NCOL  32
#define NSEQ  4096

typedef __attribute__((ext_vector_type(4))) float  f32x4;
typedef __attribute__((ext_vector_type(8))) short  bf16x8;

// ---------------- K0: Bt[col*KPAD + k] = bf16(W[k][col]) -------------------
__global__ __launch_bounds__(256) void k0_bt(const float* __restrict__ J,
                                             __hip_bfloat16* __restrict__ Bt) {
    int idx = blockIdx.x * 256 + threadIdx.x;     // 32*8704 = 278528 = 1088*256
    int col = idx / KPAD;
    int k   = idx - col * KPAD;
    float v = 0.f;
    if (col < QA && k < KVAL)
        v = J[(size_t)(8400 + col) * 10752 + k];  // contiguous in k -> coalesced
    Bt[idx] = __float2bfloat16(v);
}

__device__ __forceinline__ short f2bf(float f) {
    __hip_bfloat16 b = __float2bfloat16(f);
    return *reinterpret_cast<short*>(&b);
}

// ---------------- K1: register-streamed MFMA GEMM, 16 waves/CU -------------
__global__ __launch_bounds__(1024, 4) void k1_mfma(const float* __restrict__ X,
                                                   const __hip_bfloat16* __restrict__ Bt,
                                                   const float* __restrict__ h,
                                                   float* __restrict__ out) {
    __shared__ float part[16][16][32];  // 32 KB: per-wave partial C
    __shared__ float lg[16][32];

    const int tid = threadIdx.x;
    const int w   = tid >> 6;           // 0..15: k-slice
    const int l   = tid & 63;
    const int row = l & 15;             // A: M-row ; B: N-col (same lane field)
    const int kg  = l >> 4;             // 0..3 k-group of 8
    const int n0  = blockIdx.x << 4;    // 16 rows/block, 256 blocks exact

    const int k0 = w * SLICE + kg * 8;  // lane's first k element

    const float* Arow = X + (size_t)(n0 + row) * KVAL;
    const __hip_bfloat16* Bc0 = Bt + (size_t)row * KPAD + k0;          // cols 0-15
    const __hip_bfloat16* Bc1 = Bt + (size_t)(row + 16) * KPAD + k0;   // cols 16-31

    f32x4  pa0[3], pa1[3];
    bf16x8 pb0[3], pb1[3];
    f32x4  acc0 = {0.f, 0.f, 0.f, 0.f};
    f32x4  acc1 = {0.f, 0.f, 0.f, 0.f};

    // A loads: nontemporal (one-pass stream). Tail k>=8400 clamps to row base;
    // contribution killed by Bt zero-padding.
    #define LDA(s, g)  __builtin_nontemporal_load(                             \
        (const f32x4*)(Arow + (((k0 + (s)*32 + (g)) < KVAL) ? (k0 + (s)*32 + (g)) : 0)))
    #define LDB0(s)    (*(const bf16x8*)(Bc0 + (s)*32))
    #define LDB1(s)    (*(const bf16x8*)(Bc1 + (s)*32))

    pa0[0] = LDA(0, 0); pa1[0] = LDA(0, 4); pb0[0] = LDB0(0); pb1[0] = LDB1(0);
    pa0[1] = LDA(1, 0); pa1[1] = LDA(1, 4); pb0[1] = LDB0(1); pb1[1] = LDB1(1);

    #pragma unroll
    for (int s = 0; s < NSTEP; ++s) {
        const int sp = s + 2;
        if (sp < NSTEP) {               // depth-2 prefetch, constant indices
            pa0[sp % 3] = LDA(sp, 0);
            pa1[sp % 3] = LDA(sp, 4);
            pb0[sp % 3] = LDB0(sp);
            pb1[sp % 3] = LDB1(sp);
        }
        const f32x4 a0 = pa0[s % 3], a1 = pa1[s % 3];
        bf16x8 af;
        af[0] = f2bf(a0[0]); af[1] = f2bf(a0[1]);
        af[2] = f2bf(a0[2]); af[3] = f2bf(a0[3]);
        af[4] = f2bf(a1[0]); af[5] = f2bf(a1[1]);
        af[6] = f2bf(a1[2]); af[7] = f2bf(a1[3]);
        acc0 = __builtin_amdgcn_mfma_f32_16x16x32_bf16(af, pb0[s % 3], acc0, 0, 0, 0);
        acc1 = __builtin_amdgcn_mfma_f32_16x16x32_bf16(af, pb1[s % 3], acc1, 0, 0, 0);
    }
    #undef LDA
    #undef LDB0
    #undef LDB1

    // C/D layout: col = lane&15, row = (lane>>4)*4 + reg  [m89-verified]
    #pragma unroll
    for (int r = 0; r < 4; ++r) {
        const int m = (kg << 2) + r;
        part[w][m][row]      = acc0[r];
        part[w][m][row + 16] = acc1[r];
    }
    __syncthreads();

    // combine 16 wave-partials + h ; softmax over q<21 per row
    if (tid < 512) {
        const int m = tid >> 5, c = tid & 31;
        float s = 0.f;
        #pragma unroll
        for (int ww = 0; ww < 16; ++ww) s += part[ww][m][c];
        lg[m][c] = s + ((c < QA) ? h[8400 + c] : 0.f);
    }
    __syncthreads();
    if (tid < 512) {
        const int m = tid >> 5, c = tid & 31;
        if (c < QA) {
            float mx = -1e30f;
            #pragma unroll
            for (int a = 0; a < QA; ++a) mx = fmaxf(mx, lg[m][a]);
            float den = 0.f;
            #pragma unroll
            for (int a = 0; a < QA; ++a) den += __expf(lg[m][a] - mx);
            out[(size_t)(n0 + m) * QA + c] = __expf(lg[m][c] - mx) / den;
        }
    }
}

extern "C" void kernel_launch(void* const* d_in, const int* in_sizes, int n_in,
                              void* d_out, int out_size, void* d_ws, size_t ws_size,
                              hipStream_t stream) {
    const float* X = (const float*)d_in[0];   // [4096,400,21] one-hot fp32
    const float* h = (const float*)d_in[1];   // [512,21]
    const float* J = (const float*)d_in[2];   // [512,21,512,21]
    float* out = (float*)d_out;               // [4096,21]

    __hip_bfloat16* Bt = (__hip_bfloat16*)d_ws;   // 32*8704 bf16 = 557056 B

    k0_bt<<<(NCOL * KPAD) / 256, 256, 0, stream>>>(J, Bt);
    k1_mfma<<<NSEQ / 16, 1024, 0, stream>>>(X, Bt, h, out);
}

// Round 11
// 60.870 us; speedup vs baseline: 1.0170x; 1.0170x over previous
//
#include <hip/hip_runtime.h>
#include <hip/hip_bf16.h>

// arDCA: out[n,q] = softmax_q( h[400,q] + sum_{j<400} J[400,q,j,tok(n,j)] )
// R11 = R9 byte-identical EXCEPT the A-stream (X) loads are nontemporal.
// Single-variable A/B: tests whether the ~3.9 TB/s read plateau is the
// L2-fill/miss-allocation path (NT skips L2 allocate for the once-read X).
// logits = X[4096 x 8400] * W[8400 x 21], W[k][q] = J[(8400+q)*10752 + k].
// K0: Bt[col(32)][k(8448)] bf16, zero-padded (540 KB, L2-resident).
// K1: 256 blocks x 512 thr; block = 16 n-rows; 8 waves split K (1056 = 33
//     steps of mfma_f32_16x16x32_bf16 x 2 q-frags); depth-2 reg prefetch.
// N=4096, RES=400, Q=21, L=512.

#define QA    21
#define KVAL  8400
#define KPAD  8448               // 8 waves * 33 steps * 32
#define NCOL  32                 // padded q-cols
#define NSEQ  4096

typedef __attribute__((ext_vector_type(4))) float  f32x4;
typedef __attribute__((ext_vector_type(8))) short  bf16x8;

// ---------------- K0: Bt[col*KPAD + k] = bf16(W[k][col]) -------------------
__global__ __launch_bounds__(256) void k0_bt(const float* __restrict__ J,
                                             __hip_bfloat16* __restrict__ Bt) {
    int idx = blockIdx.x * 256 + threadIdx.x;     // 32*8448 = 270336 = 1056*256
    int col = idx / KPAD;
    int k   = idx - col * KPAD;
    float v = 0.f;
    if (col < QA && k < KVAL)
        v = J[(size_t)(8400 + col) * 10752 + k];  // contiguous in k -> coalesced
    Bt[idx] = __float2bfloat16(v);
}

__device__ __forceinline__ short f2bf(float f) {
    __hip_bfloat16 b = __float2bfloat16(f);
    return *reinterpret_cast<short*>(&b);
}

// ---------------- K1: register-streamed MFMA GEMM --------------------------
__global__ __launch_bounds__(512) void k1_mfma(const float* __restrict__ X,
                                               const __hip_bfloat16* __restrict__ Bt,
                                               const float* __restrict__ h,
                                               float* __restrict__ out) {
    __shared__ float part[8][16][32];   // 16 KB: per-wave partial C
    __shared__ float lg[16][32];

    const int tid = threadIdx.x;
    const int w   = tid >> 6;           // 0..7: k-slice
    const int l   = tid & 63;
    const int row = l & 15;             // A: M-row ; B: N-col (same lane field)
    const int kg  = l >> 4;             // 0..3 k-group of 8
    const int n0  = blockIdx.x << 4;    // 16 rows/block, 256 blocks exact

    const int k0 = w * 1056 + kg * 8;   // lane's first k element

    const float* Arow = X + (size_t)(n0 + row) * KVAL;          // row base
    const __hip_bfloat16* Bc0 = Bt + (size_t)row * KPAD + k0;          // cols 0-15
    const __hip_bfloat16* Bc1 = Bt + (size_t)(row + 16) * KPAD + k0;   // cols 16-31

    f32x4  pa0[3], pa1[3];
    bf16x8 pb0[3], pb1[3];
    f32x4  acc0 = {0.f, 0.f, 0.f, 0.f};
    f32x4  acc1 = {0.f, 0.f, 0.f, 0.f};

    // A loads NONTEMPORAL (one-pass stream, skip L2 allocate). Tail k>=8400
    // clamps to row base; contribution killed by Bt zero-padding.
    #define LDA(s, g)  __builtin_nontemporal_load(                             \
        (const f32x4*)(Arow + (((k0 + (s)*32 + (g)) < KVAL) ? (k0 + (s)*32 + (g)) : 0)))
    #define LDB0(s)    (*(const bf16x8*)(Bc0 + (s)*32))
    #define LDB1(s)    (*(const bf16x8*)(Bc1 + (s)*32))

    // prologue: steps 0,1
    pa0[0] = LDA(0, 0); pa1[0] = LDA(0, 4); pb0[0] = LDB0(0); pb1[0] = LDB1(0);
    pa0[1] = LDA(1, 0); pa1[1] = LDA(1, 4); pb0[1] = LDB0(1); pb1[1] = LDB1(1);

    #pragma unroll
    for (int s = 0; s < 33; ++s) {
        const int sp = s + 2;
        if (sp < 33) {                  // depth-2 prefetch (constant idx: full unroll)
            pa0[sp % 3] = LDA(sp, 0);
            pa1[sp % 3] = LDA(sp, 4);
            pb0[sp % 3] = LDB0(sp);
            pb1[sp % 3] = LDB1(sp);
        }
        const f32x4 a0 = pa0[s % 3], a1 = pa1[s % 3];
        bf16x8 af;
        af[0] = f2bf(a0[0]); af[1] = f2bf(a0[1]);
        af[2] = f2bf(a0[2]); af[3] = f2bf(a0[3]);
        af[4] = f2bf(a1[0]); af[5] = f2bf(a1[1]);
        af[6] = f2bf(a1[2]); af[7] = f2bf(a1[3]);
        acc0 = __builtin_amdgcn_mfma_f32_16x16x32_bf16(af, pb0[s % 3], acc0, 0, 0, 0);
        acc1 = __builtin_amdgcn_mfma_f32_16x16x32_bf16(af, pb1[s % 3], acc1, 0, 0, 0);
    }
    #undef LDA
    #undef LDB0
    #undef LDB1

    // C/D layout: col = lane&15, row = (lane>>4)*4 + reg  [m89-verified]
    #pragma unroll
    for (int r = 0; r < 4; ++r) {
        const int m = (kg << 2) + r;
        part[w][m][row]      = acc0[r];
        part[w][m][row + 16] = acc1[r];
    }
    __syncthreads();

    // combine 8 wave-partials + h ; then softmax over q<21 per row
    {
        const int m = tid >> 5, c = tid & 31;
        float s = 0.f;
        #pragma unroll
        for (int ww = 0; ww < 8; ++ww) s += part[ww][m][c];
        lg[m][c] = s + ((c < QA) ? h[8400 + c] : 0.f);
    }
    __syncthreads();
    {
        const int m = tid >> 5, c = tid & 31;
        if (c < QA) {
            float mx = -1e30f;
            #pragma unroll
            for (int a = 0; a < QA; ++a) mx = fmaxf(mx, lg[m][a]);
            float den = 0.f;
            #pragma unroll
            for (int a = 0; a < QA; ++a) den += __expf(lg[m][a] - mx);
            out[(size_t)(n0 + m) * QA + c] = __expf(lg[m][c] - mx) / den;
        }
    }
}

extern "C" void kernel_launch(void* const* d_in, const int* in_sizes, int n_in,
                              void* d_out, int out_size, void* d_ws, size_t ws_size,
                              hipStream_t stream) {
    const float* X = (const float*)d_in[0];   // [4096,400,21] one-hot fp32
    const float* h = (const float*)d_in[1];   // [512,21]
    const float* J = (const float*)d_in[2];   // [512,21,512,21]
    float* out = (float*)d_out;               // [4096,21]

    __hip_bfloat16* Bt = (__hip_bfloat16*)d_ws;   // 32*8448 bf16 = 540672 B

    k0_bt<<<(NCOL * KPAD) / 256, 256, 0, stream>>>(J, Bt);
    k1_mfma<<<NSEQ / 16, 512, 0, stream>>>(X, Bt, h, out);
}

// Round 12
// 38.865 us; speedup vs baseline: 1.5929x; 1.5662x over previous
//
#include <hip/hip_runtime.h>
#include <hip/hip_bf16.h>

// arDCA: out[n,q] = softmax_q( h[400,q] + sum_{j<400} J[400,q,j,tok(n,j)] )
// R12 = R9 byte-identical EXCEPT prefetch depth 2 -> 4 (ring of 5).
// Single-variable test: is the ~3.9 TB/s X-read plateau a latency-distance
// artifact (depth-2 = ~200 cyc tolerance vs ~900 cyc HBM latency)?
// logits = X[4096 x 8400] * W[8400 x 21], W[k][q] = J[(8400+q)*10752 + k].
// K0: Bt[col(32)][k(8448)] bf16, zero-padded (540 KB, L2-resident).
// K1: 256 blocks x 512 thr; block = 16 n-rows; 8 waves split K (1056 = 33
//     steps of mfma_f32_16x16x32_bf16 x 2 q-frags); depth-4 reg prefetch.
// N=4096, RES=400, Q=21, L=512.

#define QA    21
#define KVAL  8400
#define KPAD  8448               // 8 waves * 33 steps * 32
#define NCOL  32                 // padded q-cols
#define NSEQ  4096

typedef __attribute__((ext_vector_type(4))) float  f32x4;
typedef __attribute__((ext_vector_type(8))) short  bf16x8;

// ---------------- K0: Bt[col*KPAD + k] = bf16(W[k][col]) -------------------
__global__ __launch_bounds__(256) void k0_bt(const float* __restrict__ J,
                                             __hip_bfloat16* __restrict__ Bt) {
    int idx = blockIdx.x * 256 + threadIdx.x;     // 32*8448 = 270336 = 1056*256
    int col = idx / KPAD;
    int k   = idx - col * KPAD;
    float v = 0.f;
    if (col < QA && k < KVAL)
        v = J[(size_t)(8400 + col) * 10752 + k];  // contiguous in k -> coalesced
    Bt[idx] = __float2bfloat16(v);
}

__device__ __forceinline__ short f2bf(float f) {
    __hip_bfloat16 b = __float2bfloat16(f);
    return *reinterpret_cast<short*>(&b);
}

// ---------------- K1: register-streamed MFMA GEMM --------------------------
__global__ __launch_bounds__(512) void k1_mfma(const float* __restrict__ X,
                                               const __hip_bfloat16* __restrict__ Bt,
                                               const float* __restrict__ h,
                                               float* __restrict__ out) {
    __shared__ float part[8][16][32];   // 16 KB: per-wave partial C
    __shared__ float lg[16][32];

    const int tid = threadIdx.x;
    const int w   = tid >> 6;           // 0..7: k-slice
    const int l   = tid & 63;
    const int row = l & 15;             // A: M-row ; B: N-col (same lane field)
    const int kg  = l >> 4;             // 0..3 k-group of 8
    const int n0  = blockIdx.x << 4;    // 16 rows/block, 256 blocks exact

    const int k0 = w * 1056 + kg * 8;   // lane's first k element

    const float* Arow = X + (size_t)(n0 + row) * KVAL;          // row base
    const __hip_bfloat16* Bc0 = Bt + (size_t)row * KPAD + k0;          // cols 0-15
    const __hip_bfloat16* Bc1 = Bt + (size_t)(row + 16) * KPAD + k0;   // cols 16-31

    f32x4  pa0[5], pa1[5];
    bf16x8 pb0[5], pb1[5];
    f32x4  acc0 = {0.f, 0.f, 0.f, 0.f};
    f32x4  acc1 = {0.f, 0.f, 0.f, 0.f};

    // A granule load with tail clamp: k >= 8400 reads row base (finite one-hot
    // data, contribution killed by Bt zero-padding). Cached (NT disproven, R11).
    #define LDA(s, g)  (*(const f32x4*)(Arow + (((k0 + (s)*32 + (g)) < KVAL) ? (k0 + (s)*32 + (g)) : 0)))
    #define LDB0(s)    (*(const bf16x8*)(Bc0 + (s)*32))
    #define LDB1(s)    (*(const bf16x8*)(Bc1 + (s)*32))

    // prologue: steps 0..3 (depth-4)
    #pragma unroll
    for (int s = 0; s < 4; ++s) {
        pa0[s] = LDA(s, 0); pa1[s] = LDA(s, 4);
        pb0[s] = LDB0(s);   pb1[s] = LDB1(s);
    }

    #pragma unroll
    for (int s = 0; s < 33; ++s) {
        const int sp = s + 4;
        if (sp < 33) {                  // depth-4 prefetch (constant idx: full unroll)
            pa0[sp % 5] = LDA(sp, 0);
            pa1[sp % 5] = LDA(sp, 4);
            pb0[sp % 5] = LDB0(sp);
            pb1[sp % 5] = LDB1(sp);
        }
        const f32x4 a0 = pa0[s % 5], a1 = pa1[s % 5];
        bf16x8 af;
        af[0] = f2bf(a0[0]); af[1] = f2bf(a0[1]);
        af[2] = f2bf(a0[2]); af[3] = f2bf(a0[3]);
        af[4] = f2bf(a1[0]); af[5] = f2bf(a1[1]);
        af[6] = f2bf(a1[2]); af[7] = f2bf(a1[3]);
        acc0 = __builtin_amdgcn_mfma_f32_16x16x32_bf16(af, pb0[s % 5], acc0, 0, 0, 0);
        acc1 = __builtin_amdgcn_mfma_f32_16x16x32_bf16(af, pb1[s % 5], acc1, 0, 0, 0);
    }
    #undef LDA
    #undef LDB0
    #undef LDB1

    // C/D layout: col = lane&15, row = (lane>>4)*4 + reg  [m89-verified]
    #pragma unroll
    for (int r = 0; r < 4; ++r) {
        const int m = (kg << 2) + r;
        part[w][m][row]      = acc0[r];
        part[w][m][row + 16] = acc1[r];
    }
    __syncthreads();

    // combine 8 wave-partials + h ; then softmax over q<21 per row
    {
        const int m = tid >> 5, c = tid & 31;
        float s = 0.f;
        #pragma unroll
        for (int ww = 0; ww < 8; ++ww) s += part[ww][m][c];
        lg[m][c] = s + ((c < QA) ? h[8400 + c] : 0.f);
    }
    __syncthreads();
    {
        const int m = tid >> 5, c = tid & 31;
        if (c < QA) {
            float mx = -1e30f;
            #pragma unroll
            for (int a = 0; a < QA; ++a) mx = fmaxf(mx, lg[m][a]);
            float den = 0.f;
            #pragma unroll
            for (int a = 0; a < QA; ++a) den += __expf(lg[m][a] - mx);
            out[(size_t)(n0 + m) * QA + c] = __expf(lg[m][c] - mx) / den;
        }
    }
}

extern "C" void kernel_launch(void* const* d_in, const int* in_sizes, int n_in,
                              void* d_out, int out_size, void* d_ws, size_t ws_size,
                              hipStream_t stream) {
    const float* X = (const float*)d_in[0];   // [4096,400,21] one-hot fp32
    const float* h = (const float*)d_in[1];   // [512,21]
    const float* J = (const float*)d_in[2];   // [512,21,512,21]
    float* out = (float*)d_out;               // [4096,21]

    __hip_bfloat16* Bt = (__hip_bfloat16*)d_ws;   // 32*8448 bf16 = 540672 B

    k0_bt<<<(NCOL * KPAD) / 256, 256, 0, stream>>>(J, Bt);
    k1_mfma<<<NSEQ / 16, 512, 0, stream>>>(X, Bt, h, out);
}